// Round 18
// baseline (518.877 us; speedup 1.0000x reference)
//
#include <hip/hip_runtime.h>
#include <hip/hip_bf16.h>

// ---------------------------------------------------------------------------
// CFGSubASTExpressionCombiner.
// Structure (r18): r17 (compact K|V projection for referenced rows only) with
// a 2-DEEP register prefetch pipeline in the kv GEMM: two reg sets fA/fB,
// loop unrolled x2, so each LDS-write waits on loads issued two compute
// phases earlier (HBM latency fully hidden). 1 barrier/tile retained.
// Pool v2: wave split k|v halves. Q proj gathers; out proj streams.
// D = 256, H = 8, HD = 32, OUT = 256.
// NOTES:
//  - no hipMemsetAsync in the graph (in-graph small fills ~235us each, r3).
//  - scan is 3-phase multi-block (single-block scan was 233us on 1 CU, r4).
//  - r14: 2 blocks/CU needs col-split -> 2x enc read -> net loss.
//  - r16: 64-row batches raised FETCH -> dur tracks bytes at ~2.4-2.7 TB/s.
//  - r17: compaction (only ~63% rows referenced) -> 484us total.
// ---------------------------------------------------------------------------

typedef __attribute__((ext_vector_type(8))) short bf16x8;
typedef __attribute__((ext_vector_type(4))) float f32x4;

#define DEV __device__ __forceinline__

DEV float bf2f(unsigned short u) {
    union { unsigned int i; float f; } x;
    x.i = ((unsigned int)u) << 16;
    return x.f;
}

DEV unsigned short f2bf(float f) {
    union { float f; unsigned int i; } x;
    x.f = f;
    unsigned int i = x.i;
    unsigned int r = 0x7fffu + ((i >> 16) & 1u);   // round-to-nearest-even
    return (unsigned short)((i + r) >> 16);
}

// 8 consecutive fp32 -> bf16x8 via v_cvt_pk_bf16_f32 (4 instrs)
DEV bf16x8 cvt8(float4 lo, float4 hi) {
    union { bf16x8 v; unsigned int u[4]; } r;
    asm("v_cvt_pk_bf16_f32 %0, %1, %2" : "=v"(r.u[0]) : "v"(lo.x), "v"(lo.y));
    asm("v_cvt_pk_bf16_f32 %0, %1, %2" : "=v"(r.u[1]) : "v"(lo.z), "v"(lo.w));
    asm("v_cvt_pk_bf16_f32 %0, %1, %2" : "=v"(r.u[2]) : "v"(hi.x), "v"(hi.y));
    asm("v_cvt_pk_bf16_f32 %0, %1, %2" : "=v"(r.u[3]) : "v"(hi.z), "v"(hi.w));
    return r.v;
}

// pack two f32 into 2 bf16 (one dword) for vector stores
DEV unsigned int pack2(float a, float b) {
    unsigned int r;
    asm("v_cvt_pk_bf16_f32 %0, %1, %2" : "=v"(r) : "v"(a), "v"(b));
    return r;
}

// XOR-swizzled LDS index (ushort units); c must be a multiple of 8 elems.
DEV int swz(int row, int c) {
    return row * 256 + ((((c) >> 3) ^ (row & 7)) << 3);
}

// ---------------------------------------------------------------------------
// Weight prep: Wt_q[256][256], Wt_kv[512][256] (K cols then V cols),
// Wt_o[256][256] in bf16 [N][K] layout; b_kv = bK|bV.
// ---------------------------------------------------------------------------
__global__ void convert_weights(const float* __restrict__ Wq,
                                const float* __restrict__ Wk,
                                const float* __restrict__ Wv,
                                const float* __restrict__ Wo,
                                const float* __restrict__ bk,
                                const float* __restrict__ bv,
                                unsigned short* __restrict__ Wtq,
                                unsigned short* __restrict__ Wtkv,
                                unsigned short* __restrict__ Wto,
                                float* __restrict__ bkv) {
    int t = blockIdx.x * 256 + threadIdx.x;
    if (t < 65536) {
        int n = t >> 8, k = t & 255;
        Wtq[t] = f2bf(Wq[k * 256 + n]);
    } else if (t < 65536 + 131072) {
        int u = t - 65536;
        int n = u >> 8, k = u & 255;
        Wtkv[u] = f2bf(n < 256 ? Wk[k * 256 + n] : Wv[k * 256 + (n - 256)]);
    } else if (t < 196608 + 65536) {
        int u = t - 196608;
        int n = u >> 8, k = u & 255;
        Wto[u] = f2bf(Wo[k * 256 + n]);
    } else if (t < 262144 + 512) {
        int c = t - 262144;
        bkv[c] = c < 256 ? bk[c] : bv[c - 256];
    }
}

// ---------------------------------------------------------------------------
__global__ void zero_kernel(int* __restrict__ p, int n) {
    int i = blockIdx.x * 256 + threadIdx.x;
    if (i < n) p[i] = 0;
}

__global__ void hist_kernel(const int* __restrict__ map_val,
                            int* __restrict__ counts, int M) {
    int m = blockIdx.x * 256 + threadIdx.x;
    if (m < M) atomicAdd(&counts[map_val[m]], 1);
}

// mark referenced ast rows
__global__ void mark_kernel(const int* __restrict__ map_key,
                            int* __restrict__ ref, int M) {
    int m = blockIdx.x * 256 + threadIdx.x;
    if (m < M) ref[map_key[m]] = 1;
}

// ---- 3-phase exclusive scan over vals[n] -> pref[n] (+ total) ----
__global__ __launch_bounds__(256) void scan_p1(const int* __restrict__ vals,
                                               int* __restrict__ bsum, int n) {
    const int i = blockIdx.x * 256 + threadIdx.x;
    int v = (i < n) ? vals[i] : 0;
#pragma unroll
    for (int d = 1; d < 64; d <<= 1) v += __shfl_xor(v, d);
    __shared__ int ws[4];
    if ((threadIdx.x & 63) == 0) ws[threadIdx.x >> 6] = v;
    __syncthreads();
    if (threadIdx.x == 0) bsum[blockIdx.x] = ws[0] + ws[1] + ws[2] + ws[3];
}

__global__ __launch_bounds__(256) void scan_p2(const int* __restrict__ bsum,
                                               int* __restrict__ bpref,
                                               int* __restrict__ total,
                                               int nb) {
    __shared__ int part[256];
    const int t = threadIdx.x;
    const int chunk = (nb + 255) / 256;
    const int lo = t * chunk;
    const int hi = min(lo + chunk, nb);
    int sum = 0;
    for (int i = lo; i < hi; ++i) sum += bsum[i];
    part[t] = sum;
    __syncthreads();
    for (int d = 1; d < 256; d <<= 1) {
        int v = (t >= d) ? part[t - d] : 0;
        __syncthreads();
        part[t] += v;
        __syncthreads();
    }
    int run = (t > 0) ? part[t - 1] : 0;
    for (int i = lo; i < hi; ++i) {
        bpref[i] = run;
        run += bsum[i];
    }
    if (t == 255) *total = part[255];
}

// writes pref[i] (and optionally a second copy cursor[i])
__global__ __launch_bounds__(256) void scan_p3(const int* __restrict__ vals,
                                               const int* __restrict__ bpref,
                                               int* __restrict__ pref,
                                               int* __restrict__ cursor, int n) {
    __shared__ int sh[256];
    const int t = threadIdx.x;
    const int i = blockIdx.x * 256 + t;
    const int v = (i < n) ? vals[i] : 0;
    sh[t] = v;
    __syncthreads();
    for (int d = 1; d < 256; d <<= 1) {
        int u = (t >= d) ? sh[t - d] : 0;
        __syncthreads();
        sh[t] += u;
        __syncthreads();
    }
    if (i < n) {
        const int e = sh[t] - v + bpref[blockIdx.x];
        pref[i] = e;
        if (cursor) cursor[i] = e;
    }
}

// build compact row list: uniq_list[roff[r]] = r for referenced rows
__global__ void uniq_kernel(const int* __restrict__ ref,
                            const int* __restrict__ roff,
                            int* __restrict__ uniq_list, int n) {
    int r = blockIdx.x * 256 + threadIdx.x;
    if (r < n && ref[r]) uniq_list[roff[r]] = r;
}

// scatter entries into CSR order, storing COMPACT row id
__global__ void scatter_kernel(const int* __restrict__ map_key,
                               const int* __restrict__ map_val,
                               const int* __restrict__ roff,
                               int* __restrict__ cursor,
                               int* __restrict__ sorted_src, int M) {
    int m = blockIdx.x * 256 + threadIdx.x;
    if (m >= M) return;
    int seg = map_val[m];
    int pos = atomicAdd(&cursor[seg], 1);
    sorted_src[pos] = roff[map_key[m]];   // compact kv row of this entry
}

// ---------------------------------------------------------------------------
// B-register streaming K|V GEMM over COMPACT rows, 2-deep prefetch pipeline.
// Block = 1024 thr (16 waves). Wave w owns output cols w*32..+31 of 512.
// B fragments loaded once from L2-resident Wtkv. A: 32 compact rows per tile
// (enc[uniq_list[i]]), double-buffered bf16 LDS (2x16KB, XOR-swizzled),
// ONE barrier per tile. Reg sets fA/fB hold tiles t+2s ahead -> LDS-write
// waits on loads issued 2 compute phases ago (HBM latency hidden).
// ---------------------------------------------------------------------------
__global__ __launch_bounds__(1024, 4) void gemm_kv_stream(
    const float* __restrict__ enc,           // [N][256] fp32
    const int* __restrict__ uniq_list,       // [U] ast row per compact id
    const int* __restrict__ Uptr,            // # referenced rows
    const unsigned short* __restrict__ Wtkv, // [512][256] bf16
    const float* __restrict__ bkv,           // [512]
    unsigned short* __restrict__ out) {      // [U][512] bf16 (compact)
    __shared__ unsigned short As[2][32 * 256];

    const int U = *Uptr;
    const int tid = threadIdx.x;
    const int wave = tid >> 6, lane = tid & 63;
    const int lrow = lane & 15;
    const int koct = (lane >> 4) * 8;
    const int colb = wave * 32;

    // ---- B into registers (once, from L2): 16 frags = 64 VGPR ----
    bf16x8 B0[8], B1[8];
#pragma unroll
    for (int kt = 0; kt < 8; ++kt) {
        B0[kt] = *(const bf16x8*)(Wtkv + (long)(colb + lrow) * 256 + kt * 32 + koct);
        B1[kt] = *(const bf16x8*)(Wtkv + (long)(colb + 16 + lrow) * 256 + kt * 32 + koct);
    }
    const float4 bs0 = *(const float4*)(bkv + colb + (lane >> 4) * 4);
    const float4 bs1 = *(const float4*)(bkv + colb + 16 + (lane >> 4) * 4);

    // A staging: 1024 thr x 8 fp32 = 32x256 tile
    const int srow = tid >> 5;        // 0..31
    const int scol = (tid & 31) * 8;  // 16B chunk

    const long ntiles = (U + 31) / 32;
    const long s = gridDim.x;

    auto loadT = [&](long tt, float4& g0, float4& g1) {
        const long g = tt * 32 + srow;
        const long src = (g < U) ? (long)uniq_list[g] : 0;
        const float* ap = enc + src * 256 + scol;
        g0 = *(const float4*)(ap);
        g1 = *(const float4*)(ap + 4);
    };

    // compute+store one staged tile
    auto compute = [&](int buf, long t) {
        f32x4 acc[2][2] = {};
#pragma unroll
        for (int kt = 0; kt < 8; ++kt) {
            const int k0 = kt * 32 + koct;
            bf16x8 a0 = *(const bf16x8*)(&As[buf][swz(lrow, k0)]);
            bf16x8 a1 = *(const bf16x8*)(&As[buf][swz(16 + lrow, k0)]);
            acc[0][0] = __builtin_amdgcn_mfma_f32_16x16x32_bf16(B0[kt], a0, acc[0][0], 0, 0, 0);
            acc[0][1] = __builtin_amdgcn_mfma_f32_16x16x32_bf16(B1[kt], a0, acc[0][1], 0, 0, 0);
            acc[1][0] = __builtin_amdgcn_mfma_f32_16x16x32_bf16(B0[kt], a1, acc[1][0], 0, 0, 0);
            acc[1][1] = __builtin_amdgcn_mfma_f32_16x16x32_bf16(B1[kt], a1, acc[1][1], 0, 0, 0);
        }
        const long rbase = t * 32;
#pragma unroll
        for (int i = 0; i < 2; ++i) {
            const long row = rbase + i * 16 + lrow;
            if (row < U) {
                unsigned short* orow = out + row * 512 + colb + (lane >> 4) * 4;
                uint2 w0, w1;
                w0.x = pack2(acc[i][0][0] + bs0.x, acc[i][0][1] + bs0.y);
                w0.y = pack2(acc[i][0][2] + bs0.z, acc[i][0][3] + bs0.w);
                w1.x = pack2(acc[i][1][0] + bs1.x, acc[i][1][1] + bs1.y);
                w1.y = pack2(acc[i][1][2] + bs1.z, acc[i][1][3] + bs1.w);
                *(uint2*)(orow)      = w0;
                *(uint2*)(orow + 16) = w1;
            }
        }
    };

    long t = blockIdx.x;
    float4 fA0, fA1, fB0, fB1;
    loadT(t, fA0, fA1);          // tile t
    loadT(t + s, fB0, fB1);      // tile t+s

    while (t < ntiles) {
        // ---- tile t (buffer 0, regs fA) ----
        *(bf16x8*)(&As[0][swz(srow, scol)]) = cvt8(fA0, fA1);
        __syncthreads();
        loadT(t + 2 * s, fA0, fA1);          // 2-deep reload
        compute(0, t);

        const long t2 = t + s;
        if (t2 < ntiles) {
            // ---- tile t+s (buffer 1, regs fB) ----
            *(bf16x8*)(&As[1][swz(srow, scol)]) = cvt8(fB0, fB1);
            __syncthreads();
            loadT(t2 + 2 * s, fB0, fB1);     // 2-deep reload
            compute(1, t2);
        }
        t += 2 * s;
    }
}

// ---------------------------------------------------------------------------
// 64-row single-barrier GEMM (gather/scatter variants for Q and out proj),
// swapped-operand epilogue (8B bf16 / 16B fp32 stores).
// ---------------------------------------------------------------------------
template <bool GATHER, bool SCATTER, bool A_F32, bool OUT_F32, int NW, int MINB>
__global__ __launch_bounds__(NW * 64, MINB) void gemm64(
    const void* __restrict__ Aptr,
    const int* __restrict__ srcIdx,
    const int* __restrict__ dstIdx,
    const unsigned short* __restrict__ Wt,   // bf16 [NW*64][256]
    const float* __restrict__ bias,          // [NW*64]
    void* __restrict__ Out,
    int nrows, int ldo) {
    __shared__ unsigned short Alds[64 * 256];

    constexpr int NT = NW * 64;
    constexpr int F = 16384 / NT;   // elems staged per thread

    const int tid = threadIdx.x;
    const long rbase = (long)blockIdx.x * 64;

    // ---- stage A tile (64 rows x 256), swizzled ----
    {
        const int l0 = tid * F;
        const int row = l0 >> 8;
        const int col0 = l0 & 255;
        long gr = rbase + row;
        if (gr > nrows - 1) gr = nrows - 1;         // safe row; stores masked
        const long src = GATHER ? (long)srcIdx[gr] : gr;
        if constexpr (A_F32) {
            const float* ap = (const float*)Aptr + src * 256 + col0;
#pragma unroll
            for (int u = 0; u < F; u += 8) {
                const float4 lo = *(const float4*)(ap + u);
                const float4 hi = *(const float4*)(ap + u + 4);
                *(bf16x8*)(&Alds[swz(row, col0 + u)]) = cvt8(lo, hi);
            }
        } else {
            const unsigned short* ap = (const unsigned short*)Aptr + src * 256 + col0;
#pragma unroll
            for (int u = 0; u < F; u += 8)
                *(bf16x8*)(&Alds[swz(row, col0 + u)]) = *(const bf16x8*)(ap + u);
        }
    }
    __syncthreads();

    // ---- compute (swapped operands) ----
    const int wave = tid >> 6, lane = tid & 63;
    const int lrow = lane & 15;
    const int koct = (lane >> 4) * 8;
    const int colb = wave * 64;

    f32x4 acc[4][4] = {};

#pragma unroll
    for (int kt = 0; kt < 8; ++kt) {
        const int k0 = kt * 32 + koct;
        bf16x8 a[4], b[4];
#pragma unroll
        for (int i = 0; i < 4; ++i)
            a[i] = *(const bf16x8*)(&Alds[swz(i * 16 + lrow, k0)]);
#pragma unroll
        for (int j = 0; j < 4; ++j)
            b[j] = *(const bf16x8*)(Wt + (long)(colb + j * 16 + lrow) * 256 + k0);
#pragma unroll
        for (int i = 0; i < 4; ++i)
#pragma unroll
            for (int j = 0; j < 4; ++j)
                acc[i][j] = __builtin_amdgcn_mfma_f32_16x16x32_bf16(b[j], a[i], acc[i][j], 0, 0, 0);
    }

    // ---- epilogue: lane holds row i*16+lrow, cols colb+j*16+(lane>>4)*4..+3
#pragma unroll
    for (int i = 0; i < 4; ++i) {
        const long row = rbase + i * 16 + lrow;
        if (row < nrows) {
            const long drow = SCATTER ? (long)dstIdx[row] : row;
#pragma unroll
            for (int j = 0; j < 4; ++j) {
                const int cb = colb + j * 16 + (lane >> 4) * 4;
                const float4 bs = *(const float4*)(bias + cb);
                if constexpr (OUT_F32) {
                    float4 v;
                    v.x = acc[i][j][0] + bs.x;
                    v.y = acc[i][j][1] + bs.y;
                    v.z = acc[i][j][2] + bs.z;
                    v.w = acc[i][j][3] + bs.w;
                    *(float4*)((float*)Out + drow * ldo + cb) = v;
                } else {
                    uint2 w;
                    w.x = pack2(acc[i][j][0] + bs.x, acc[i][j][1] + bs.y);
                    w.y = pack2(acc[i][j][2] + bs.z, acc[i][j][3] + bs.w);
                    *(uint2*)((unsigned short*)Out + drow * ldo + cb) = w;
                }
            }
        }
    }
}

// ---------------------------------------------------------------------------
// CSR pooling v2: one wave per segment. Lane l reads 16B of the compact kv
// row: lanes 0-31 hold k, lanes 32-63 hold v. k-half computes the per-head
// dot (4-lane groups), shfl hands ew to the v-half, v-half accumulates and
// writes the 16B output chunk.
// ---------------------------------------------------------------------------
__global__ __launch_bounds__(512) void pool_csr_kernel(
    unsigned short* __restrict__ q,          // bf16 [S][256] (in: q, out: pooled)
    const unsigned short* __restrict__ kv,   // bf16 [U][512] compact (k | v)
    const int* __restrict__ offsets,         // [S+1]
    const int* __restrict__ sorted_src,      // [M] compact kv row per entry
    int S) {
    const int s = blockIdx.x * 8 + (threadIdx.x >> 6);
    if (s >= S) return;
    const int lane = threadIdx.x & 63;
    const int j = lane & 31;
    const int beg = offsets[s];
    const int end = offsets[s + 1];

    // k lanes hold q chunk [j*8, j*8+8) as floats
    float qf[8];
    if (lane < 32) {
        bf16x8 q8 = *(const bf16x8*)(q + (long)s * 256 + j * 8);
#pragma unroll
        for (int tt = 0; tt < 8; ++tt)
            qf[tt] = bf2f(((const unsigned short*)&q8)[tt]);
    }

    float acc[8] = {0.f, 0.f, 0.f, 0.f, 0.f, 0.f, 0.f, 0.f};
    float denom = 0.f;

    long mrow = (beg < end) ? (long)sorted_src[beg] : 0;
    for (int e = beg; e < end; ++e) {
        const long mnext = (e + 1 < end) ? (long)sorted_src[e + 1] : 0;
        const bf16x8 r = *(const bf16x8*)(kv + mrow * 512 + lane * 8);
        mrow = mnext;

        float ew = 0.f;
        if (lane < 32) {
            float sc = 0.f;
#pragma unroll
            for (int tt = 0; tt < 8; ++tt)
                sc += qf[tt] * bf2f(((const unsigned short*)&r)[tt]);
            sc += __shfl_xor(sc, 1);
            sc += __shfl_xor(sc, 2);   // 4-lane group (head j>>2) holds the dot
            ew = expf(sc * 0.17677669529663687f);  // 1/sqrt(32)
            denom += ew;
        }
        const float ewv = __shfl(ew, j);   // v lane 32+j <- ew from k lane j
        if (lane >= 32) {
#pragma unroll
            for (int tt = 0; tt < 8; ++tt)
                acc[tt] += ewv * bf2f(((const unsigned short*)&r)[tt]);
        }
    }

    const float dn = __shfl(denom, j);
    if (lane >= 32) {
        const float w = 1.0f / fmaxf(dn, 1e-9f);
        uint4 o;
        o.x = pack2(acc[0] * w, acc[1] * w);
        o.y = pack2(acc[2] * w, acc[3] * w);
        o.z = pack2(acc[4] * w, acc[5] * w);
        o.w = pack2(acc[6] * w, acc[7] * w);
        *(uint4*)(q + (long)s * 256 + j * 8) = o;
    }
}

// ---------------------------------------------------------------------------
extern "C" void kernel_launch(void* const* d_in, const int* in_sizes, int n_in,
                              void* d_out, int out_size, void* d_ws, size_t ws_size,
                              hipStream_t stream) {
    const float* enc  = (const float*)d_in[0];
    const float* W_q  = (const float*)d_in[1];
    const float* b_q  = (const float*)d_in[2];
    const float* W_k  = (const float*)d_in[3];
    const float* b_k  = (const float*)d_in[4];
    const float* W_v  = (const float*)d_in[5];
    const float* b_v  = (const float*)d_in[6];
    const float* W_o  = (const float*)d_in[7];
    const float* b_o  = (const float*)d_in[8];
    const int* map_key = (const int*)d_in[9];    // [M] ast idx
    const int* map_val = (const int*)d_in[10];   // [M] cfg idx (segment id)
    const int* pdg_key = (const int*)d_in[11];   // [S] dst rows (bijection)
    const int* pdg_val = (const int*)d_in[12];   // [S] src ast rows

    const int M = in_sizes[9];
    const int S = in_sizes[11];
    const int NAST = in_sizes[0] / 256;
    const int NBS = (S + 255) / 256;
    const int NBR = (NAST + 255) / 256;

    char* ws = (char*)d_ws;
    size_t off = 0;
    auto alloc = [&](size_t bytes) -> char* {
        char* p = ws + off;
        off += (bytes + 255) & ~(size_t)255;
        return p;
    };

    unsigned short* Wt_q  = (unsigned short*)alloc(256 * 256 * 2);
    unsigned short* Wt_kv = (unsigned short*)alloc(512 * 256 * 2);
    unsigned short* Wt_o  = (unsigned short*)alloc(256 * 256 * 2);
    float*          b_kv  = (float*)alloc(512 * 4);
    int*            counts  = (int*)alloc((size_t)S * 4);
    int*            cursor  = (int*)alloc((size_t)S * 4);
    int*            offsets = (int*)alloc((size_t)(S + 1) * 4);
    int*            sbsum   = (int*)alloc((size_t)NBS * 4);
    int*            sbpref  = (int*)alloc((size_t)NBS * 4);
    int*            ref     = (int*)alloc((size_t)NAST * 4);
    int*            roff    = (int*)alloc((size_t)(NAST + 1) * 4);   // +U at end
    int*            rbsum   = (int*)alloc((size_t)NBR * 4);
    int*            rbpref  = (int*)alloc((size_t)NBR * 4);
    int*            uniq_list  = (int*)alloc((size_t)NAST * 4);
    int*            sorted_src = (int*)alloc((size_t)M * 4);
    unsigned short* qbuf   = (unsigned short*)alloc((size_t)S * 256 * 2);   // q, then pooled
    unsigned short* kv_all = (unsigned short*)alloc((size_t)NAST * 512 * 2);

    // zero counts + ref with plain kernels (NOT hipMemsetAsync)
    zero_kernel<<<NBS, 256, 0, stream>>>(counts, S);
    zero_kernel<<<NBR, 256, 0, stream>>>(ref, NAST);

    convert_weights<<<(262656 + 255) / 256, 256, 0, stream>>>(
        W_q, W_k, W_v, W_o, b_k, b_v, Wt_q, Wt_kv, Wt_o, b_kv);

    // mark referenced rows + segment histogram
    mark_kernel<<<(M + 255) / 256, 256, 0, stream>>>(map_key, ref, M);
    hist_kernel<<<(M + 255) / 256, 256, 0, stream>>>(map_val, counts, M);

    // segment CSR scan: counts -> offsets, cursor
    scan_p1<<<NBS, 256, 0, stream>>>(counts, sbsum, S);
    scan_p2<<<1, 256, 0, stream>>>(sbsum, sbpref, offsets + S, NBS);
    scan_p3<<<NBS, 256, 0, stream>>>(counts, sbpref, offsets, cursor, S);

    // row-compaction scan: ref -> roff, U = roff[NAST]
    scan_p1<<<NBR, 256, 0, stream>>>(ref, rbsum, NAST);
    scan_p2<<<1, 256, 0, stream>>>(rbsum, rbpref, roff + NAST, NBR);
    scan_p3<<<NBR, 256, 0, stream>>>(ref, rbpref, roff, (int*)nullptr, NAST);
    uniq_kernel<<<NBR, 256, 0, stream>>>(ref, roff, uniq_list, NAST);

    // scatter entries into CSR order with COMPACT kv row ids
    scatter_kernel<<<(M + 255) / 256, 256, 0, stream>>>(
        map_key, map_val, roff, cursor, sorted_src, M);

    // K|V projection for REFERENCED rows only (compact), 2-deep pipeline
    gemm_kv_stream<<<256, 1024, 0, stream>>>(
        enc, uniq_list, roff + NAST, Wt_kv, b_kv, kv_all);

    // Q projection: q[pdg_key[i]] = enc[pdg_val[i]] @ W_q + b_q (gather fp32)
    gemm64<true, true, true, false, 4, 4><<<(S + 63) / 64, 256, 0, stream>>>(
        enc, pdg_val, pdg_key, Wt_q, b_q, qbuf, S, 256);

    // CSR segment softmax + pooling (compact kv rows); overwrites qbuf
    pool_csr_kernel<<<(S + 7) / 8, 512, 0, stream>>>(
        qbuf, kv_all, offsets, sorted_src, S);

    // output projection to d_out (fp32), streaming bf16 A
    gemm64<false, false, false, true, 4, 4><<<(S + 63) / 64, 256, 0, stream>>>(
        qbuf, nullptr, nullptr, Wt_o, b_o, d_out, S, 256);
}

// Round 19
// 464.554 us; speedup vs baseline: 1.1169x; 1.1169x over previous
//
#include <hip/hip_runtime.h>
#include <hip/hip_bf16.h>

// ---------------------------------------------------------------------------
// CFGSubASTExpressionCombiner.
// Structure (r19): r17 (compact K|V projection, 1-deep pipeline — best
// measured) + merged mark/hist pass + 2-entry-unrolled pool loop (pair of
// kv-row loads in flight together). r18's 2-deep kv pipeline regressed
// (519 vs 484) -> reverted.
// D = 256, H = 8, HD = 32, OUT = 256.
// NOTES:
//  - no hipMemsetAsync in the graph (in-graph small fills ~235us each, r3).
//  - scan is 3-phase multi-block (single-block scan was 233us on 1 CU, r4).
//  - r14: 2 blocks/CU needs col-split -> 2x enc read -> net loss.
//  - r16: 64-row batches raised FETCH -> dur tracks bytes at ~2.4-2.7 TB/s.
//  - r17: compaction (only ~63% rows referenced) -> 484us total (best).
//  - r18: 2-deep reg pipeline in kv -> regressed; kv is bytes-limited.
// ---------------------------------------------------------------------------

typedef __attribute__((ext_vector_type(8))) short bf16x8;
typedef __attribute__((ext_vector_type(4))) float f32x4;

#define DEV __device__ __forceinline__

DEV float bf2f(unsigned short u) {
    union { unsigned int i; float f; } x;
    x.i = ((unsigned int)u) << 16;
    return x.f;
}

DEV unsigned short f2bf(float f) {
    union { float f; unsigned int i; } x;
    x.f = f;
    unsigned int i = x.i;
    unsigned int r = 0x7fffu + ((i >> 16) & 1u);   // round-to-nearest-even
    return (unsigned short)((i + r) >> 16);
}

// 8 consecutive fp32 -> bf16x8 via v_cvt_pk_bf16_f32 (4 instrs)
DEV bf16x8 cvt8(float4 lo, float4 hi) {
    union { bf16x8 v; unsigned int u[4]; } r;
    asm("v_cvt_pk_bf16_f32 %0, %1, %2" : "=v"(r.u[0]) : "v"(lo.x), "v"(lo.y));
    asm("v_cvt_pk_bf16_f32 %0, %1, %2" : "=v"(r.u[1]) : "v"(lo.z), "v"(lo.w));
    asm("v_cvt_pk_bf16_f32 %0, %1, %2" : "=v"(r.u[2]) : "v"(hi.x), "v"(hi.y));
    asm("v_cvt_pk_bf16_f32 %0, %1, %2" : "=v"(r.u[3]) : "v"(hi.z), "v"(hi.w));
    return r.v;
}

// pack two f32 into 2 bf16 (one dword) for vector stores
DEV unsigned int pack2(float a, float b) {
    unsigned int r;
    asm("v_cvt_pk_bf16_f32 %0, %1, %2" : "=v"(r) : "v"(a), "v"(b));
    return r;
}

// XOR-swizzled LDS index (ushort units); c must be a multiple of 8 elems.
DEV int swz(int row, int c) {
    return row * 256 + ((((c) >> 3) ^ (row & 7)) << 3);
}

// ---------------------------------------------------------------------------
// Weight prep: Wt_q[256][256], Wt_kv[512][256] (K cols then V cols),
// Wt_o[256][256] in bf16 [N][K] layout; b_kv = bK|bV.
// ---------------------------------------------------------------------------
__global__ void convert_weights(const float* __restrict__ Wq,
                                const float* __restrict__ Wk,
                                const float* __restrict__ Wv,
                                const float* __restrict__ Wo,
                                const float* __restrict__ bk,
                                const float* __restrict__ bv,
                                unsigned short* __restrict__ Wtq,
                                unsigned short* __restrict__ Wtkv,
                                unsigned short* __restrict__ Wto,
                                float* __restrict__ bkv) {
    int t = blockIdx.x * 256 + threadIdx.x;
    if (t < 65536) {
        int n = t >> 8, k = t & 255;
        Wtq[t] = f2bf(Wq[k * 256 + n]);
    } else if (t < 65536 + 131072) {
        int u = t - 65536;
        int n = u >> 8, k = u & 255;
        Wtkv[u] = f2bf(n < 256 ? Wk[k * 256 + n] : Wv[k * 256 + (n - 256)]);
    } else if (t < 196608 + 65536) {
        int u = t - 196608;
        int n = u >> 8, k = u & 255;
        Wto[u] = f2bf(Wo[k * 256 + n]);
    } else if (t < 262144 + 512) {
        int c = t - 262144;
        bkv[c] = c < 256 ? bk[c] : bv[c - 256];
    }
}

// ---------------------------------------------------------------------------
__global__ void zero_kernel(int* __restrict__ p, int n) {
    int i = blockIdx.x * 256 + threadIdx.x;
    if (i < n) p[i] = 0;
}

// merged: mark referenced rows AND histogram segments in one pass
__global__ void markhist_kernel(const int* __restrict__ map_key,
                                const int* __restrict__ map_val,
                                int* __restrict__ ref,
                                int* __restrict__ counts, int M) {
    int m = blockIdx.x * 256 + threadIdx.x;
    if (m < M) {
        ref[map_key[m]] = 1;
        atomicAdd(&counts[map_val[m]], 1);
    }
}

// ---- 3-phase exclusive scan over vals[n] -> pref[n] (+ total) ----
__global__ __launch_bounds__(256) void scan_p1(const int* __restrict__ vals,
                                               int* __restrict__ bsum, int n) {
    const int i = blockIdx.x * 256 + threadIdx.x;
    int v = (i < n) ? vals[i] : 0;
#pragma unroll
    for (int d = 1; d < 64; d <<= 1) v += __shfl_xor(v, d);
    __shared__ int ws[4];
    if ((threadIdx.x & 63) == 0) ws[threadIdx.x >> 6] = v;
    __syncthreads();
    if (threadIdx.x == 0) bsum[blockIdx.x] = ws[0] + ws[1] + ws[2] + ws[3];
}

__global__ __launch_bounds__(256) void scan_p2(const int* __restrict__ bsum,
                                               int* __restrict__ bpref,
                                               int* __restrict__ total,
                                               int nb) {
    __shared__ int part[256];
    const int t = threadIdx.x;
    const int chunk = (nb + 255) / 256;
    const int lo = t * chunk;
    const int hi = min(lo + chunk, nb);
    int sum = 0;
    for (int i = lo; i < hi; ++i) sum += bsum[i];
    part[t] = sum;
    __syncthreads();
    for (int d = 1; d < 256; d <<= 1) {
        int v = (t >= d) ? part[t - d] : 0;
        __syncthreads();
        part[t] += v;
        __syncthreads();
    }
    int run = (t > 0) ? part[t - 1] : 0;
    for (int i = lo; i < hi; ++i) {
        bpref[i] = run;
        run += bsum[i];
    }
    if (t == 255) *total = part[255];
}

// writes pref[i] (and optionally a second copy cursor[i])
__global__ __launch_bounds__(256) void scan_p3(const int* __restrict__ vals,
                                               const int* __restrict__ bpref,
                                               int* __restrict__ pref,
                                               int* __restrict__ cursor, int n) {
    __shared__ int sh[256];
    const int t = threadIdx.x;
    const int i = blockIdx.x * 256 + t;
    const int v = (i < n) ? vals[i] : 0;
    sh[t] = v;
    __syncthreads();
    for (int d = 1; d < 256; d <<= 1) {
        int u = (t >= d) ? sh[t - d] : 0;
        __syncthreads();
        sh[t] += u;
        __syncthreads();
    }
    if (i < n) {
        const int e = sh[t] - v + bpref[blockIdx.x];
        pref[i] = e;
        if (cursor) cursor[i] = e;
    }
}

// build compact row list: uniq_list[roff[r]] = r for referenced rows
__global__ void uniq_kernel(const int* __restrict__ ref,
                            const int* __restrict__ roff,
                            int* __restrict__ uniq_list, int n) {
    int r = blockIdx.x * 256 + threadIdx.x;
    if (r < n && ref[r]) uniq_list[roff[r]] = r;
}

// scatter entries into CSR order, storing COMPACT row id
__global__ void scatter_kernel(const int* __restrict__ map_key,
                               const int* __restrict__ map_val,
                               const int* __restrict__ roff,
                               int* __restrict__ cursor,
                               int* __restrict__ sorted_src, int M) {
    int m = blockIdx.x * 256 + threadIdx.x;
    if (m >= M) return;
    int seg = map_val[m];
    int pos = atomicAdd(&cursor[seg], 1);
    sorted_src[pos] = roff[map_key[m]];   // compact kv row of this entry
}

// ---------------------------------------------------------------------------
// B-register streaming K|V GEMM over COMPACT rows (r17 body, 1-deep).
// Block = 1024 thr (16 waves). Wave w owns output cols w*32..+31 of 512.
// B fragments loaded once from L2-resident Wtkv. A: 32 compact rows per tile
// (enc[uniq_list[i]]), double-buffered bf16 LDS (2x16KB, XOR-swizzled),
// ONE barrier per tile. Row count U read from device (roff[NAST]).
// ---------------------------------------------------------------------------
__global__ __launch_bounds__(1024, 4) void gemm_kv_stream(
    const float* __restrict__ enc,           // [N][256] fp32
    const int* __restrict__ uniq_list,       // [U] ast row per compact id
    const int* __restrict__ Uptr,            // # referenced rows
    const unsigned short* __restrict__ Wtkv, // [512][256] bf16
    const float* __restrict__ bkv,           // [512]
    unsigned short* __restrict__ out) {      // [U][512] bf16 (compact)
    __shared__ unsigned short As[2][32 * 256];

    const int U = *Uptr;
    const int tid = threadIdx.x;
    const int wave = tid >> 6, lane = tid & 63;
    const int lrow = lane & 15;
    const int koct = (lane >> 4) * 8;
    const int colb = wave * 32;

    // ---- B into registers (once, from L2): 16 frags = 64 VGPR ----
    bf16x8 B0[8], B1[8];
#pragma unroll
    for (int kt = 0; kt < 8; ++kt) {
        B0[kt] = *(const bf16x8*)(Wtkv + (long)(colb + lrow) * 256 + kt * 32 + koct);
        B1[kt] = *(const bf16x8*)(Wtkv + (long)(colb + 16 + lrow) * 256 + kt * 32 + koct);
    }
    const float4 bs0 = *(const float4*)(bkv + colb + (lane >> 4) * 4);
    const float4 bs1 = *(const float4*)(bkv + colb + 16 + (lane >> 4) * 4);

    // A staging: 1024 thr x 8 fp32 = 32x256 tile
    const int srow = tid >> 5;        // 0..31
    const int scol = (tid & 31) * 8;  // 16B chunk

    const long ntiles = (U + 31) / 32;
    const int stride = gridDim.x;
    long t = blockIdx.x;

    // prologue: load tile t into regs
    float4 f0, f1;
    {
        const long g = t * 32 + srow;
        const long src = (g < U) ? (long)uniq_list[g] : 0;
        const float* ap = enc + src * 256 + scol;
        f0 = *(const float4*)(ap);
        f1 = *(const float4*)(ap + 4);
    }

    int cur = 0;
    while (t < ntiles) {
        // write A(t) into current buffer (swizzled)
        *(bf16x8*)(&As[cur][swz(srow, scol)]) = cvt8(f0, f1);
        __syncthreads();

        // issue A(t+stride) loads -> complete during compute
        const long tn = t + stride;
        {
            long g = tn * 32 + srow;
            long src = (g < U) ? (long)uniq_list[g] : 0;
            const float* ap = enc + src * 256 + scol;
            f0 = *(const float4*)(ap);
            f1 = *(const float4*)(ap + 4);
        }

        // compute: A from LDS, B from registers
        f32x4 acc[2][2] = {};
#pragma unroll
        for (int kt = 0; kt < 8; ++kt) {
            const int k0 = kt * 32 + koct;
            bf16x8 a0 = *(const bf16x8*)(&As[cur][swz(lrow, k0)]);
            bf16x8 a1 = *(const bf16x8*)(&As[cur][swz(16 + lrow, k0)]);
            acc[0][0] = __builtin_amdgcn_mfma_f32_16x16x32_bf16(B0[kt], a0, acc[0][0], 0, 0, 0);
            acc[0][1] = __builtin_amdgcn_mfma_f32_16x16x32_bf16(B1[kt], a0, acc[0][1], 0, 0, 0);
            acc[1][0] = __builtin_amdgcn_mfma_f32_16x16x32_bf16(B0[kt], a1, acc[1][0], 0, 0, 0);
            acc[1][1] = __builtin_amdgcn_mfma_f32_16x16x32_bf16(B1[kt], a1, acc[1][1], 0, 0, 0);
        }

        // stores (compact rows): lane owns rows {t*32+i*16+lrow}
        const long rbase = t * 32;
#pragma unroll
        for (int i = 0; i < 2; ++i) {
            const long row = rbase + i * 16 + lrow;
            if (row < U) {
                unsigned short* orow = out + row * 512 + colb + (lane >> 4) * 4;
                uint2 w0, w1;
                w0.x = pack2(acc[i][0][0] + bs0.x, acc[i][0][1] + bs0.y);
                w0.y = pack2(acc[i][0][2] + bs0.z, acc[i][0][3] + bs0.w);
                w1.x = pack2(acc[i][1][0] + bs1.x, acc[i][1][1] + bs1.y);
                w1.y = pack2(acc[i][1][2] + bs1.z, acc[i][1][3] + bs1.w);
                *(uint2*)(orow)      = w0;
                *(uint2*)(orow + 16) = w1;
            }
        }

        cur ^= 1;
        t = tn;
    }
}

// ---------------------------------------------------------------------------
// 64-row single-barrier GEMM (gather/scatter variants for Q and out proj),
// swapped-operand epilogue (8B bf16 / 16B fp32 stores).
// ---------------------------------------------------------------------------
template <bool GATHER, bool SCATTER, bool A_F32, bool OUT_F32, int NW, int MINB>
__global__ __launch_bounds__(NW * 64, MINB) void gemm64(
    const void* __restrict__ Aptr,
    const int* __restrict__ srcIdx,
    const int* __restrict__ dstIdx,
    const unsigned short* __restrict__ Wt,   // bf16 [NW*64][256]
    const float* __restrict__ bias,          // [NW*64]
    void* __restrict__ Out,
    int nrows, int ldo) {
    __shared__ unsigned short Alds[64 * 256];

    constexpr int NT = NW * 64;
    constexpr int F = 16384 / NT;   // elems staged per thread

    const int tid = threadIdx.x;
    const long rbase = (long)blockIdx.x * 64;

    // ---- stage A tile (64 rows x 256), swizzled ----
    {
        const int l0 = tid * F;
        const int row = l0 >> 8;
        const int col0 = l0 & 255;
        long gr = rbase + row;
        if (gr > nrows - 1) gr = nrows - 1;         // safe row; stores masked
        const long src = GATHER ? (long)srcIdx[gr] : gr;
        if constexpr (A_F32) {
            const float* ap = (const float*)Aptr + src * 256 + col0;
#pragma unroll
            for (int u = 0; u < F; u += 8) {
                const float4 lo = *(const float4*)(ap + u);
                const float4 hi = *(const float4*)(ap + u + 4);
                *(bf16x8*)(&Alds[swz(row, col0 + u)]) = cvt8(lo, hi);
            }
        } else {
            const unsigned short* ap = (const unsigned short*)Aptr + src * 256 + col0;
#pragma unroll
            for (int u = 0; u < F; u += 8)
                *(bf16x8*)(&Alds[swz(row, col0 + u)]) = *(const bf16x8*)(ap + u);
        }
    }
    __syncthreads();

    // ---- compute (swapped operands) ----
    const int wave = tid >> 6, lane = tid & 63;
    const int lrow = lane & 15;
    const int koct = (lane >> 4) * 8;
    const int colb = wave * 64;

    f32x4 acc[4][4] = {};

#pragma unroll
    for (int kt = 0; kt < 8; ++kt) {
        const int k0 = kt * 32 + koct;
        bf16x8 a[4], b[4];
#pragma unroll
        for (int i = 0; i < 4; ++i)
            a[i] = *(const bf16x8*)(&Alds[swz(i * 16 + lrow, k0)]);
#pragma unroll
        for (int j = 0; j < 4; ++j)
            b[j] = *(const bf16x8*)(Wt + (long)(colb + j * 16 + lrow) * 256 + k0);
#pragma unroll
        for (int i = 0; i < 4; ++i)
#pragma unroll
            for (int j = 0; j < 4; ++j)
                acc[i][j] = __builtin_amdgcn_mfma_f32_16x16x32_bf16(b[j], a[i], acc[i][j], 0, 0, 0);
    }

    // ---- epilogue: lane holds row i*16+lrow, cols colb+j*16+(lane>>4)*4..+3
#pragma unroll
    for (int i = 0; i < 4; ++i) {
        const long row = rbase + i * 16 + lrow;
        if (row < nrows) {
            const long drow = SCATTER ? (long)dstIdx[row] : row;
#pragma unroll
            for (int j = 0; j < 4; ++j) {
                const int cb = colb + j * 16 + (lane >> 4) * 4;
                const float4 bs = *(const float4*)(bias + cb);
                if constexpr (OUT_F32) {
                    float4 v;
                    v.x = acc[i][j][0] + bs.x;
                    v.y = acc[i][j][1] + bs.y;
                    v.z = acc[i][j][2] + bs.z;
                    v.w = acc[i][j][3] + bs.w;
                    *(float4*)((float*)Out + drow * ldo + cb) = v;
                } else {
                    uint2 w;
                    w.x = pack2(acc[i][j][0] + bs.x, acc[i][j][1] + bs.y);
                    w.y = pack2(acc[i][j][2] + bs.z, acc[i][j][3] + bs.w);
                    *(uint2*)((unsigned short*)Out + drow * ldo + cb) = w;
                }
            }
        }
    }
}

// ---------------------------------------------------------------------------
// CSR pooling v3: one wave per segment, 2-entry unrolled (both kv-row loads
// in flight before compute). Lane l reads 16B of the compact kv row:
// lanes 0-31 hold k, lanes 32-63 hold v. k-half computes the per-head dot
// (4-lane groups), shfl hands ew to the v-half, v-half accumulates and
// writes the 16B output chunk.
// ---------------------------------------------------------------------------
__global__ __launch_bounds__(512) void pool_csr_kernel(
    unsigned short* __restrict__ q,          // bf16 [S][256] (in: q, out: pooled)
    const unsigned short* __restrict__ kv,   // bf16 [U][512] compact (k | v)
    const int* __restrict__ offsets,         // [S+1]
    const int* __restrict__ sorted_src,      // [M] compact kv row per entry
    int S) {
    const int s = blockIdx.x * 8 + (threadIdx.x >> 6);
    if (s >= S) return;
    const int lane = threadIdx.x & 63;
    const int j = lane & 31;
    const int beg = offsets[s];
    const int end = offsets[s + 1];

    // k lanes hold q chunk [j*8, j*8+8) as floats
    float qf[8];
    if (lane < 32) {
        bf16x8 q8 = *(const bf16x8*)(q + (long)s * 256 + j * 8);
#pragma unroll
        for (int tt = 0; tt < 8; ++tt)
            qf[tt] = bf2f(((const unsigned short*)&q8)[tt]);
    }

    float acc[8] = {0.f, 0.f, 0.f, 0.f, 0.f, 0.f, 0.f, 0.f};
    float denom = 0.f;

    auto process = [&](const bf16x8& r) {
        float ew = 0.f;
        if (lane < 32) {
            float sc = 0.f;
#pragma unroll
            for (int tt = 0; tt < 8; ++tt)
                sc += qf[tt] * bf2f(((const unsigned short*)&r)[tt]);
            sc += __shfl_xor(sc, 1);
            sc += __shfl_xor(sc, 2);   // 4-lane group (head j>>2) holds the dot
            ew = expf(sc * 0.17677669529663687f);  // 1/sqrt(32)
            denom += ew;
        }
        const float ewv = __shfl(ew, j);   // v lane 32+j <- ew from k lane j
        if (lane >= 32) {
#pragma unroll
            for (int tt = 0; tt < 8; ++tt)
                acc[tt] += ewv * bf2f(((const unsigned short*)&r)[tt]);
        }
    };

    int e = beg;
    long i0 = (e < end) ? (long)sorted_src[e] : 0;
    while (e + 1 < end) {
        const long i1 = sorted_src[e + 1];
        const bf16x8 r0 = *(const bf16x8*)(kv + i0 * 512 + lane * 8);
        const bf16x8 r1 = *(const bf16x8*)(kv + i1 * 512 + lane * 8);
        i0 = (e + 2 < end) ? (long)sorted_src[e + 2] : 0;
        process(r0);
        process(r1);
        e += 2;
    }
    if (e < end) {
        const bf16x8 r0 = *(const bf16x8*)(kv + i0 * 512 + lane * 8);
        process(r0);
    }

    const float dn = __shfl(denom, j);
    if (lane >= 32) {
        const float w = 1.0f / fmaxf(dn, 1e-9f);
        uint4 o;
        o.x = pack2(acc[0] * w, acc[1] * w);
        o.y = pack2(acc[2] * w, acc[3] * w);
        o.z = pack2(acc[4] * w, acc[5] * w);
        o.w = pack2(acc[6] * w, acc[7] * w);
        *(uint4*)(q + (long)s * 256 + j * 8) = o;
    }
}

// ---------------------------------------------------------------------------
extern "C" void kernel_launch(void* const* d_in, const int* in_sizes, int n_in,
                              void* d_out, int out_size, void* d_ws, size_t ws_size,
                              hipStream_t stream) {
    const float* enc  = (const float*)d_in[0];
    const float* W_q  = (const float*)d_in[1];
    const float* b_q  = (const float*)d_in[2];
    const float* W_k  = (const float*)d_in[3];
    const float* b_k  = (const float*)d_in[4];
    const float* W_v  = (const float*)d_in[5];
    const float* b_v  = (const float*)d_in[6];
    const float* W_o  = (const float*)d_in[7];
    const float* b_o  = (const float*)d_in[8];
    const int* map_key = (const int*)d_in[9];    // [M] ast idx
    const int* map_val = (const int*)d_in[10];   // [M] cfg idx (segment id)
    const int* pdg_key = (const int*)d_in[11];   // [S] dst rows (bijection)
    const int* pdg_val = (const int*)d_in[12];   // [S] src ast rows

    const int M = in_sizes[9];
    const int S = in_sizes[11];
    const int NAST = in_sizes[0] / 256;
    const int NBS = (S + 255) / 256;
    const int NBR = (NAST + 255) / 256;

    char* ws = (char*)d_ws;
    size_t off = 0;
    auto alloc = [&](size_t bytes) -> char* {
        char* p = ws + off;
        off += (bytes + 255) & ~(size_t)255;
        return p;
    };

    unsigned short* Wt_q  = (unsigned short*)alloc(256 * 256 * 2);
    unsigned short* Wt_kv = (unsigned short*)alloc(512 * 256 * 2);
    unsigned short* Wt_o  = (unsigned short*)alloc(256 * 256 * 2);
    float*          b_kv  = (float*)alloc(512 * 4);
    int*            counts  = (int*)alloc((size_t)S * 4);
    int*            cursor  = (int*)alloc((size_t)S * 4);
    int*            offsets = (int*)alloc((size_t)(S + 1) * 4);
    int*            sbsum   = (int*)alloc((size_t)NBS * 4);
    int*            sbpref  = (int*)alloc((size_t)NBS * 4);
    int*            ref     = (int*)alloc((size_t)NAST * 4);
    int*            roff    = (int*)alloc((size_t)(NAST + 1) * 4);   // +U at end
    int*            rbsum   = (int*)alloc((size_t)NBR * 4);
    int*            rbpref  = (int*)alloc((size_t)NBR * 4);
    int*            uniq_list  = (int*)alloc((size_t)NAST * 4);
    int*            sorted_src = (int*)alloc((size_t)M * 4);
    unsigned short* qbuf   = (unsigned short*)alloc((size_t)S * 256 * 2);   // q, then pooled
    unsigned short* kv_all = (unsigned short*)alloc((size_t)NAST * 512 * 2);

    // zero counts + ref with plain kernels (NOT hipMemsetAsync)
    zero_kernel<<<NBS, 256, 0, stream>>>(counts, S);
    zero_kernel<<<NBR, 256, 0, stream>>>(ref, NAST);

    convert_weights<<<(262656 + 255) / 256, 256, 0, stream>>>(
        W_q, W_k, W_v, W_o, b_k, b_v, Wt_q, Wt_kv, Wt_o, b_kv);

    // mark referenced rows + segment histogram (one pass)
    markhist_kernel<<<(M + 255) / 256, 256, 0, stream>>>(
        map_key, map_val, ref, counts, M);

    // segment CSR scan: counts -> offsets, cursor
    scan_p1<<<NBS, 256, 0, stream>>>(counts, sbsum, S);
    scan_p2<<<1, 256, 0, stream>>>(sbsum, sbpref, offsets + S, NBS);
    scan_p3<<<NBS, 256, 0, stream>>>(counts, sbpref, offsets, cursor, S);

    // row-compaction scan: ref -> roff, U = roff[NAST]
    scan_p1<<<NBR, 256, 0, stream>>>(ref, rbsum, NAST);
    scan_p2<<<1, 256, 0, stream>>>(rbsum, rbpref, roff + NAST, NBR);
    scan_p3<<<NBR, 256, 0, stream>>>(ref, rbpref, roff, (int*)nullptr, NAST);
    uniq_kernel<<<NBR, 256, 0, stream>>>(ref, roff, uniq_list, NAST);

    // scatter entries into CSR order with COMPACT kv row ids
    scatter_kernel<<<(M + 255) / 256, 256, 0, stream>>>(
        map_key, map_val, roff, cursor, sorted_src, M);

    // K|V projection for REFERENCED rows only (compact), 1-deep pipeline
    gemm_kv_stream<<<256, 1024, 0, stream>>>(
        enc, uniq_list, roff + NAST, Wt_kv, b_kv, kv_all);

    // Q projection: q[pdg_key[i]] = enc[pdg_val[i]] @ W_q + b_q (gather fp32)
    gemm64<true, true, true, false, 4, 4><<<(S + 63) / 64, 256, 0, stream>>>(
        enc, pdg_val, pdg_key, Wt_q, b_q, qbuf, S, 256);

    // CSR segment softmax + pooling (compact kv rows); overwrites qbuf
    pool_csr_kernel<<<(S + 7) / 8, 512, 0, stream>>>(
        qbuf, kv_all, offsets, sorted_src, S);

    // output projection to d_out (fp32), streaming bf16 A
    gemm64<false, false, false, true, 4, 4><<<(S + 63) / 64, 256, 0, stream>>>(
        qbuf, nullptr, nullptr, Wt_o, b_o, d_out, S, 256);
}